// Round 1
// 567.160 us; speedup vs baseline: 1.1113x; 1.1113x over previous
//
#include <hip/hip_runtime.h>

// ChannelPair2D: out[p, k] = x[p, II[k]] * x[p, JJ[k]] for k over triu(C=64, k=1),
// pairs in row-major order. P = 16*64*64 = 65536 pixels, NPAIR = 2016.
//
// v2: block-per-pixel with LDS staging. The v1 kernel was bound on vector-memory
// ADDRESS throughput: ~5 lane-divergent global_load_dword per thread = 165M
// per-lane addresses (~270 us of addresser occupancy at ~1 addr/cyc/CU).
// Here the pixel's 256-byte channel window is loaded with ONE coalesced 64-lane
// load into LDS; all operand gathers become ds_read_b32 (LDS has free per-lane
// addressing). Stores remain perfectly coalesced global_store_dwordx4.

constexpr int C     = 64;
constexpr int NPAIR = C * (C - 1) / 2;  // 2016
constexpr int NP4   = NPAIR / 4;        // 504 float4 per pixel

__global__ __launch_bounds__(256)
void channel_pair_kernel(const float* __restrict__ x,
                         float4* __restrict__ out) {
    __shared__ float lx[C];
    const int pixel = blockIdx.x;
    const int t     = threadIdx.x;

    // One coalesced 256-byte load: lanes 0..63 of wave 0 fetch the whole pixel.
    if (t < C) lx[t] = x[pixel * C + t];
    __syncthreads();

    float4* __restrict__ po = out + (size_t)pixel * NP4;

    // 504 float4s per pixel, 256 threads -> 2 quads per thread (2nd predicated).
    #pragma unroll
    for (int r = 0; r < 2; ++r) {
        const int q = t + r * 256;
        if (q < NP4) {
            const int k = q << 2;  // first of 4 consecutive pair indices

            // Row offsets: S(i) = i*(127-i)/2 (always even product -> exact).
            // Seed i from the quadratic root, then exact integer fixup.
            float disc = 16129.0f - 8.0f * (float)k;   // 127^2 - 8k, exact in fp32
            int i = (int)((127.0f - sqrtf(disc)) * 0.5f);
            if (i < 0) i = 0;
            if (i > C - 2) i = C - 2;
            while (i > 0 && (i * (127 - i)) / 2 > k) --i;
            while (((i + 1) * (126 - i)) / 2 <= k) ++i;
            int j = i + 1 + (k - (i * (127 - i)) / 2);

            float xi = lx[i];
            float4 rr;
            rr.x = xi * lx[j]; ++j;
            if (j == C) { ++i; xi = lx[i]; j = i + 1; }
            rr.y = xi * lx[j]; ++j;
            if (j == C) { ++i; xi = lx[i]; j = i + 1; }
            rr.z = xi * lx[j]; ++j;
            if (j == C) { ++i; xi = lx[i]; j = i + 1; }
            rr.w = xi * lx[j];

            po[q] = rr;   // coalesced global_store_dwordx4
        }
    }
}

extern "C" void kernel_launch(void* const* d_in, const int* in_sizes, int n_in,
                              void* d_out, int out_size, void* d_ws, size_t ws_size,
                              hipStream_t stream) {
    const float* x  = (const float*)d_in[0];
    float4* out     = (float4*)d_out;
    // Same arithmetic as v1 (which verified): out_size/4 float4s total,
    // NP4 float4s per pixel -> npix = 65,536.
    int npix = out_size / (NP4 * 4);
    channel_pair_kernel<<<npix, 256, 0, stream>>>(x, out);
}